// Round 6
// baseline (130.707 us; speedup 1.0000x reference)
//
#include <hip/hip_runtime.h>
#include <hip/hip_bf16.h>
#include <math.h>

#define N_NODES 30000
#define MAXN 32
#define DIM 128
#define NHEAD 4
#define HDIM 32
#define NPB 16           // nodes per block in fused attn+fc kernel
#define LN_EPS 1e-5f

typedef __hip_bfloat16 bf16;
typedef __attribute__((ext_vector_type(8))) short bf16x8;
typedef __attribute__((ext_vector_type(4))) float f32x4;

__device__ inline short bfbits(float f) {
    bf16 b = __float2bfloat16(f);
    return *(short*)&b;
}
__device__ inline float bf_hi(uint w) { return __uint_as_float(w & 0xffff0000u); }
__device__ inline float bf_lo(uint w) { return __uint_as_float((w & 0xffffu) << 16); }

// ---------------- prep: W[k][n] f32 -> WT[n][k] bf16 for Wq,Wk,Wv,Wfc ----------------
__global__ __launch_bounds__(128) void prep_kernel(
    const float* __restrict__ Wq, const float* __restrict__ Wk,
    const float* __restrict__ Wv, const float* __restrict__ Wfc,
    bf16* __restrict__ WqT, bf16* __restrict__ WkT,
    bf16* __restrict__ WvT, bf16* __restrict__ WfcT)
{
    const int n = blockIdx.x, k = threadIdx.x;
    WqT[n * DIM + k]  = __float2bfloat16(Wq[k * DIM + n]);
    WkT[n * DIM + k]  = __float2bfloat16(Wk[k * DIM + n]);
    WvT[n * DIM + k]  = __float2bfloat16(Wv[k * DIM + n]);
    WfcT[n * DIM + k] = __float2bfloat16(Wfc[k * DIM + n]);
}

// ---------------- Kernel 1: QKV projection via MFMA ----------------
__device__ inline void gemm_pass(const bf16x8 a[4], const bf16* __restrict__ WT,
                                 int rl, int kb, f32x4 acc[8]) {
#pragma unroll
    for (int ks = 0; ks < 4; ++ks) {
        const bf16* wp = WT + (size_t)rl * DIM + ks * 32 + kb * 8;
#pragma unroll
        for (int t = 0; t < 8; ++t) {
            bf16x8 bfrag = *(const bf16x8*)(wp + (size_t)t * 16 * DIM);
            acc[t] = __builtin_amdgcn_mfma_f32_16x16x32_bf16(a[ks], bfrag, acc[t], 0, 0, 0);
        }
    }
}

__global__ __launch_bounds__(256) void qkv_mfma_kernel(
    const float* __restrict__ h,
    const bf16* __restrict__ WqT,
    const bf16* __restrict__ WkT,
    const bf16* __restrict__ WvT,
    float* __restrict__ Qout,
    bf16* __restrict__ Kout,
    bf16* __restrict__ Vout)
{
    const int lane = threadIdx.x & 63;
    const int wid  = threadIdx.x >> 6;
    const int r0w  = blockIdx.x * 64 + wid * 16;
    const int rl = lane & 15;
    const int kb = lane >> 4;

    const int arow = min(r0w + rl, N_NODES - 1);
    const float* hrow = h + (size_t)arow * DIM + kb * 8;
    bf16x8 a[4];
#pragma unroll
    for (int ks = 0; ks < 4; ++ks) {
        float4 f0 = *(const float4*)(hrow + ks * 32);
        float4 f1 = *(const float4*)(hrow + ks * 32 + 4);
        bf16x8 v;
        v[0] = bfbits(f0.x); v[1] = bfbits(f0.y); v[2] = bfbits(f0.z); v[3] = bfbits(f0.w);
        v[4] = bfbits(f1.x); v[5] = bfbits(f1.y); v[6] = bfbits(f1.z); v[7] = bfbits(f1.w);
        a[ks] = v;
    }

    f32x4 acc[8];

    // ---- Q ----
#pragma unroll
    for (int t = 0; t < 8; ++t) acc[t] = (f32x4){0.f, 0.f, 0.f, 0.f};
    gemm_pass(a, WqT, rl, kb, acc);
#pragma unroll
    for (int j = 0; j < 4; ++j) {
        const int row = r0w + kb * 4 + j;
        if (row < N_NODES) {
            float* orow = Qout + (size_t)row * DIM;
#pragma unroll
            for (int t = 0; t < 8; ++t) orow[rl + 16 * t] = acc[t][j];
        }
    }

    // ---- K ----
#pragma unroll
    for (int t = 0; t < 8; ++t) acc[t] = (f32x4){0.f, 0.f, 0.f, 0.f};
    gemm_pass(a, WkT, rl, kb, acc);
#pragma unroll
    for (int j = 0; j < 4; ++j) {
        const int row = r0w + kb * 4 + j;
        if (row < N_NODES) {
            bf16* orow = Kout + (size_t)row * DIM;
#pragma unroll
            for (int t = 0; t < 8; ++t) orow[rl + 16 * t] = __float2bfloat16(acc[t][j]);
        }
    }

    // ---- V ----
#pragma unroll
    for (int t = 0; t < 8; ++t) acc[t] = (f32x4){0.f, 0.f, 0.f, 0.f};
    gemm_pass(a, WvT, rl, kb, acc);
#pragma unroll
    for (int j = 0; j < 4; ++j) {
        const int row = r0w + kb * 4 + j;
        if (row < N_NODES) {
            bf16* orow = Vout + (size_t)row * DIM;
#pragma unroll
            for (int t = 0; t < 8; ++t) orow[rl + 16 * t] = __float2bfloat16(acc[t][j]);
        }
    }
}

__device__ inline float dot8(uint4 kd, const float4* qp, float acc) {
    float4 qa = qp[0], qb = qp[1];
    acc = fmaf(qa.x, bf_lo(kd.x), acc);
    acc = fmaf(qa.y, bf_hi(kd.x), acc);
    acc = fmaf(qa.z, bf_lo(kd.y), acc);
    acc = fmaf(qa.w, bf_hi(kd.y), acc);
    acc = fmaf(qb.x, bf_lo(kd.z), acc);
    acc = fmaf(qb.y, bf_hi(kd.z), acc);
    acc = fmaf(qb.z, bf_lo(kd.w), acc);
    acc = fmaf(qb.w, bf_hi(kd.w), acc);
    return acc;
}

// ---------------- Kernel 2: fused gather-attention + FC + GELU + LN ----------------
// 512 threads = 8 waves = 16 nodes (32 threads/node).
__global__ __launch_bounds__(512, 8) void attn_fc_kernel(
    const float* __restrict__ Qbuf,       // d_out currently holds Q
    const bf16* __restrict__ Kbuf,
    const bf16* __restrict__ Vbuf,
    const int* __restrict__ nidx,
    const int* __restrict__ nmask,
    const bf16* __restrict__ WfcT,        // [n][k] bf16
    const float* __restrict__ bfc,
    const float* __restrict__ gamma,
    const float* __restrict__ beta,
    float* __restrict__ out)
{
    __shared__ float qs[NPB][132];            // padded: conflict-free col reads
    __shared__ float al[NPB][NHEAD][33];      // padded: conflict-free PV reads
    __shared__ bf16  rv[NPB][136];            // padded: conflict-free b128 reads
    __shared__ int   idx_s[NPB][MAXN];
    __shared__ float red[8][NPB][2];
    __shared__ float tot[NPB][2];

    const int t    = threadIdx.x;
    const int b    = blockIdx.x;
    const int w    = t >> 6;       // wave 0..7
    const int lane = t & 63;
    const int g    = t >> 5;       // node slot 0..15
    const int q5   = t & 31;       // lane within node group

    // ---- Phase A: Q rows + neighbor indices into LDS ----
    {
        float4 v = ((const float4*)(Qbuf + (size_t)b * NPB * DIM))[t];
        *(float4*)(&qs[t >> 5][(t & 31) * 4]) = v;
        idx_s[t >> 5][t & 31] = nidx[(size_t)b * (NPB * MAXN) + t];
    }
    __syncthreads();

    // ---- Phase B: scores + softmax; thread = (node g, neighbor m) ----
    {
        const int m   = q5;
        const int src = idx_s[g][m];
        const int msk = nmask[(size_t)b * (NPB * MAXN) + g * MAXN + m];
        const uint4* krow = (const uint4*)((const ushort*)Kbuf + (size_t)src * DIM);

        float sc[NHEAD];
#pragma unroll
        for (int hh = 0; hh < NHEAD; ++hh) {
            const float4* qp = (const float4*)(&qs[g][hh * HDIM]);
            float acc = 0.f;
            acc = dot8(krow[hh * 4 + 0], qp + 0, acc);
            acc = dot8(krow[hh * 4 + 1], qp + 2, acc);
            acc = dot8(krow[hh * 4 + 2], qp + 4, acc);
            acc = dot8(krow[hh * 4 + 3], qp + 6, acc);
            acc *= 0.17677669529663687f;       // 1/sqrt(32)
            sc[hh] = (msk == 0) ? -1e9f : acc;
        }

        float mx[NHEAD], ex[NHEAD], sm[NHEAD];
#pragma unroll
        for (int hh = 0; hh < NHEAD; ++hh) mx[hh] = sc[hh];
#pragma unroll
        for (int off = 1; off < 32; off <<= 1) {
#pragma unroll
            for (int hh = 0; hh < NHEAD; ++hh)
                mx[hh] = fmaxf(mx[hh], __shfl_xor(mx[hh], off));
        }
#pragma unroll
        for (int hh = 0; hh < NHEAD; ++hh) { ex[hh] = __expf(sc[hh] - mx[hh]); sm[hh] = ex[hh]; }
#pragma unroll
        for (int off = 1; off < 32; off <<= 1) {
#pragma unroll
            for (int hh = 0; hh < NHEAD; ++hh)
                sm[hh] += __shfl_xor(sm[hh], off);
        }
#pragma unroll
        for (int hh = 0; hh < NHEAD; ++hh)
            al[g][hh][m] = ex[hh] / sm[hh];
    }
    __syncthreads();

    // ---- Phase C: PV; thread = (node g, dim quad q5) ----
    {
        const int dq = q5;                  // dims 4*dq .. 4*dq+3
        const int hh = dq >> 3;
        const float* alp = &al[g][hh][0];
        float a0 = 0.f, a1 = 0.f, a2 = 0.f, a3 = 0.f;
#pragma unroll 4
        for (int m = 0; m < MAXN; ++m) {
            uint2 v = *(const uint2*)((const ushort*)Vbuf + (size_t)idx_s[g][m] * DIM + dq * 4);
            float alv = alp[m];
            a0 = fmaf(alv, bf_lo(v.x), a0);
            a1 = fmaf(alv, bf_hi(v.x), a1);
            a2 = fmaf(alv, bf_lo(v.y), a2);
            a3 = fmaf(alv, bf_hi(v.y), a3);
        }
        uint lo = (uint)(ushort)bfbits(a0) | ((uint)(ushort)bfbits(a1) << 16);
        uint hi = (uint)(ushort)bfbits(a2) | ((uint)(ushort)bfbits(a3) << 16);
        uint2 pk; pk.x = lo; pk.y = hi;
        *(uint2*)(&rv[g][dq * 4]) = pk;
    }
    __syncthreads();

    // ---- Phase E: FC via MFMA; wave w = column tile w ----
    const int rl = lane & 15;
    const int kb = lane >> 4;
    const int col = 16 * w + rl;

    f32x4 acc = (f32x4){0.f, 0.f, 0.f, 0.f};
#pragma unroll
    for (int ks = 0; ks < 4; ++ks) {
        bf16x8 af = *(const bf16x8*)(&rv[rl][ks * 32 + kb * 8]);
        bf16x8 bfr = *(const bf16x8*)(WfcT + (size_t)col * DIM + ks * 32 + kb * 8);
        acc = __builtin_amdgcn_mfma_f32_16x16x32_bf16(af, bfr, acc, 0, 0, 0);
    }

    // ---- Phase F: +bias +residual, GELU, LayerNorm, store ----
    const float bfc_c = bfc[col];
    const float gam_c = gamma[col];
    const float bet_c = beta[col];

    float g4[4], p1[4], p2[4];
#pragma unroll
    for (int j = 0; j < 4; ++j) {
        const int row = kb * 4 + j;
        float x = acc[j] + bfc_c + qs[row][col];
        float gg = 0.5f * x * (1.0f + erff(x * 0.70710678118654752f));
        g4[j] = gg;
        p1[j] = gg;
        p2[j] = gg * gg;
    }
#pragma unroll
    for (int off = 1; off < 16; off <<= 1) {
#pragma unroll
        for (int j = 0; j < 4; ++j) {
            p1[j] += __shfl_xor(p1[j], off);
            p2[j] += __shfl_xor(p2[j], off);
        }
    }
    if (rl == 0) {
#pragma unroll
        for (int j = 0; j < 4; ++j) {
            red[w][kb * 4 + j][0] = p1[j];
            red[w][kb * 4 + j][1] = p2[j];
        }
    }
    __syncthreads();
    if (t < NPB) {
        float s1 = 0.f, s2 = 0.f;
#pragma unroll
        for (int ww = 0; ww < 8; ++ww) { s1 += red[ww][t][0]; s2 += red[ww][t][1]; }
        float mean = s1 * (1.0f / DIM);
        float var  = s2 * (1.0f / DIM) - mean * mean;
        tot[t][0] = mean;
        tot[t][1] = rsqrtf(var + LN_EPS);
    }
    __syncthreads();
#pragma unroll
    for (int j = 0; j < 4; ++j) {
        const int row = kb * 4 + j;
        float mean = tot[row][0];
        float invs = tot[row][1];
        out[((size_t)b * NPB + row) * DIM + col] = (g4[j] - mean) * invs * gam_c + bet_c;
    }
}

extern "C" void kernel_launch(void* const* d_in, const int* in_sizes, int n_in,
                              void* d_out, int out_size, void* d_ws, size_t ws_size,
                              hipStream_t stream) {
    (void)in_sizes; (void)n_in; (void)out_size; (void)ws_size;
    const float* h     = (const float*)d_in[0];
    const float* Wq    = (const float*)d_in[1];
    const float* Wk    = (const float*)d_in[2];
    const float* Wv    = (const float*)d_in[3];
    const float* Wfc   = (const float*)d_in[4];
    const float* bfc   = (const float*)d_in[5];
    const float* gamma = (const float*)d_in[6];
    const float* beta  = (const float*)d_in[7];
    const int* nidx    = (const int*)d_in[8];
    const int* nmask   = (const int*)d_in[9];

    bf16* Kbuf  = (bf16*)d_ws;
    bf16* Vbuf  = Kbuf + (size_t)N_NODES * DIM;
    bf16* WqT   = Vbuf + (size_t)N_NODES * DIM;
    bf16* WkT   = WqT + (size_t)DIM * DIM;
    bf16* WvT   = WkT + (size_t)DIM * DIM;
    bf16* WfcT  = WvT + (size_t)DIM * DIM;
    float* Q    = (float*)d_out;

    prep_kernel<<<DIM, DIM, 0, stream>>>(Wq, Wk, Wv, Wfc, WqT, WkT, WvT, WfcT);
    qkv_mfma_kernel<<<(N_NODES + 63) / 64, 256, 0, stream>>>(h, WqT, WkT, WvT, Q, Kbuf, Vbuf);
    attn_fc_kernel<<<N_NODES / NPB, 512, 0, stream>>>(Q, Kbuf, Vbuf, nidx, nmask,
                                                      WfcT, bfc, gamma, beta, (float*)d_out);
}

// Round 7
// 120.843 us; speedup vs baseline: 1.0816x; 1.0816x over previous
//
#include <hip/hip_runtime.h>
#include <hip/hip_fp16.h>
#include <math.h>

#define N_NODES 30000
#define MAXN 32
#define DIM 128
#define NHEAD 4
#define HDIM 32
#define NPB 4            // nodes per block in fused attn+fc kernel
#define LN_EPS 1e-5f

typedef _Float16 f16;
typedef __attribute__((ext_vector_type(8))) _Float16 f16x8;
typedef __attribute__((ext_vector_type(4))) float f32x4;

static __device__ __forceinline__ __half2 as_h2(uint u) { return __builtin_bit_cast(__half2, u); }
static __device__ __forceinline__ uint as_u(__half2 h) { return __builtin_bit_cast(uint, h); }
static __device__ __forceinline__ f16x8 as_f16x8(uint4 u) { return __builtin_bit_cast(f16x8, u); }

// ---------------- prep: W[k][n] f32 -> WT[n][k] f16 for Wq,Wk,Wv,Wfc ----------------
__global__ __launch_bounds__(128) void prep_kernel(
    const float* __restrict__ Wq, const float* __restrict__ Wk,
    const float* __restrict__ Wv, const float* __restrict__ Wfc,
    f16* __restrict__ WqT, f16* __restrict__ WkT,
    f16* __restrict__ WvT, f16* __restrict__ WfcT)
{
    const int n = blockIdx.x, k = threadIdx.x;
    WqT[n * DIM + k]  = (f16)Wq[k * DIM + n];
    WkT[n * DIM + k]  = (f16)Wk[k * DIM + n];
    WvT[n * DIM + k]  = (f16)Wv[k * DIM + n];
    WfcT[n * DIM + k] = (f16)Wfc[k * DIM + n];
}

// ---------------- Kernel 1: QKV projection via MFMA (f16) ----------------
__device__ inline void gemm_pass(const f16x8 a[4], const f16* __restrict__ WT,
                                 int rl, int kb, f32x4 acc[8]) {
#pragma unroll
    for (int ks = 0; ks < 4; ++ks) {
        const f16* wp = WT + (size_t)rl * DIM + ks * 32 + kb * 8;
#pragma unroll
        for (int t = 0; t < 8; ++t) {
            f16x8 bfrag = *(const f16x8*)(wp + (size_t)t * 16 * DIM);
            acc[t] = __builtin_amdgcn_mfma_f32_16x16x32_f16(a[ks], bfrag, acc[t], 0, 0, 0);
        }
    }
}

__global__ __launch_bounds__(256) void qkv_mfma_kernel(
    const float* __restrict__ h,
    const f16* __restrict__ WqT,
    const f16* __restrict__ WkT,
    const f16* __restrict__ WvT,
    f16* __restrict__ Qout,
    f16* __restrict__ Kout,
    f16* __restrict__ Vout)
{
    const int lane = threadIdx.x & 63;
    const int wid  = threadIdx.x >> 6;
    const int r0w  = blockIdx.x * 64 + wid * 16;
    const int rl = lane & 15;
    const int kb = lane >> 4;

    const int arow = min(r0w + rl, N_NODES - 1);
    const float* hrow = h + (size_t)arow * DIM + kb * 8;
    f16x8 a[4];
#pragma unroll
    for (int ks = 0; ks < 4; ++ks) {
        float4 f0 = *(const float4*)(hrow + ks * 32);
        float4 f1 = *(const float4*)(hrow + ks * 32 + 4);
        f16x8 v;
        v[0] = (f16)f0.x; v[1] = (f16)f0.y; v[2] = (f16)f0.z; v[3] = (f16)f0.w;
        v[4] = (f16)f1.x; v[5] = (f16)f1.y; v[6] = (f16)f1.z; v[7] = (f16)f1.w;
        a[ks] = v;
    }

    f32x4 acc[8];

    // ---- Q ----
#pragma unroll
    for (int t = 0; t < 8; ++t) acc[t] = (f32x4){0.f, 0.f, 0.f, 0.f};
    gemm_pass(a, WqT, rl, kb, acc);
#pragma unroll
    for (int j = 0; j < 4; ++j) {
        const int row = r0w + kb * 4 + j;
        if (row < N_NODES) {
            f16* orow = Qout + (size_t)row * DIM;
#pragma unroll
            for (int t = 0; t < 8; ++t) orow[rl + 16 * t] = (f16)acc[t][j];
        }
    }

    // ---- K ----
#pragma unroll
    for (int t = 0; t < 8; ++t) acc[t] = (f32x4){0.f, 0.f, 0.f, 0.f};
    gemm_pass(a, WkT, rl, kb, acc);
#pragma unroll
    for (int j = 0; j < 4; ++j) {
        const int row = r0w + kb * 4 + j;
        if (row < N_NODES) {
            f16* orow = Kout + (size_t)row * DIM;
#pragma unroll
            for (int t = 0; t < 8; ++t) orow[rl + 16 * t] = (f16)acc[t][j];
        }
    }

    // ---- V ----
#pragma unroll
    for (int t = 0; t < 8; ++t) acc[t] = (f32x4){0.f, 0.f, 0.f, 0.f};
    gemm_pass(a, WvT, rl, kb, acc);
#pragma unroll
    for (int j = 0; j < 4; ++j) {
        const int row = r0w + kb * 4 + j;
        if (row < N_NODES) {
            f16* orow = Vout + (size_t)row * DIM;
#pragma unroll
            for (int t = 0; t < 8; ++t) orow[rl + 16 * t] = (f16)acc[t][j];
        }
    }
}

// ---------------- Kernel 2: fused gather-attention + FC + GELU + LN ----------------
// 512 threads, NPB=4 nodes (128 threads/node) — round-5 phase shapes + fp16 packed math.
__global__ __launch_bounds__(512, 8) void attn_fc_kernel(
    const f16* __restrict__ Qh,          // [N][128] fp16 (ws)
    const f16* __restrict__ Kh,
    const f16* __restrict__ Vh,
    const int* __restrict__ nidx,
    const int* __restrict__ nmask,
    const f16* __restrict__ WfcT,        // [n][k] fp16
    const float* __restrict__ bfc,
    const float* __restrict__ gamma,
    const float* __restrict__ beta,
    float* __restrict__ out)
{
    __shared__ uint qsh[NPB][68];          // Q rows as half2 (64 uints + pad)
    __shared__ uint al_u[NPB][NHEAD][33];  // alpha as dup-half2
    __shared__ uint pv1[NPB][64];          // PV partial (part 1), half2
    __shared__ uint rv_u[16][68];          // attn out rows as half2 (rows 4..15 garbage)
    __shared__ int  idx_s[NPB][MAXN];
    __shared__ float red[8][NPB][2];
    __shared__ float tot[NPB][2];

    const int t    = threadIdx.x;
    const int b    = blockIdx.x;
    const int w    = t >> 6;        // wave 0..7
    const int lane = t & 63;
    const int nn   = t >> 7;        // node slot 0..3 (phases B/C)
    const int tl   = t & 127;       // thread within node

    // ---- Phase A: Q rows (fp16) + neighbor indices into LDS ----
    if (t < NPB * 64) {
        qsh[t >> 6][t & 63] = ((const uint*)Qh)[(size_t)b * (NPB * 64) + t];
    }
    if (t < NPB * MAXN) {
        idx_s[t >> 5][t & 31] = nidx[(size_t)b * (NPB * MAXN) + t];
    }
    __syncthreads();

    // ---- Phase B: scores + softmax; thread = (node nn, head hh, neighbor m) ----
    {
        const int hh = tl >> 5;
        const int m  = tl & 31;
        const int src = idx_s[nn][m];
        const uint4* krow = (const uint4*)(Kh + (size_t)src * DIM + hh * HDIM);
        const uint4* qrow = (const uint4*)(&qsh[nn][hh * 16]);

        __half2 a2 = as_h2(0u);
#pragma unroll
        for (int c = 0; c < 4; ++c) {
            uint4 kd = krow[c];
            uint4 qd = qrow[c];
            a2 = __hfma2(as_h2(qd.x), as_h2(kd.x), a2);
            a2 = __hfma2(as_h2(qd.y), as_h2(kd.y), a2);
            a2 = __hfma2(as_h2(qd.z), as_h2(kd.z), a2);
            a2 = __hfma2(as_h2(qd.w), as_h2(kd.w), a2);
        }
        float acc = __half2float(__low2half(a2)) + __half2float(__high2half(a2));
        acc *= 0.17677669529663687f;            // 1/sqrt(32)
        if (nmask[(size_t)b * (NPB * MAXN) + nn * MAXN + m] == 0) acc = -1e9f;

        float mx = acc;
#pragma unroll
        for (int off = 1; off < 32; off <<= 1)
            mx = fmaxf(mx, __shfl_xor(mx, off));
        float e = __expf(acc - mx);
        float s = e;
#pragma unroll
        for (int off = 1; off < 32; off <<= 1)
            s += __shfl_xor(s, off);
        float a = e / s;
        uint ah = (uint)__half_as_ushort(__float2half(a));
        al_u[nn][hh][m] = ah | (ah << 16);
    }
    __syncthreads();

    // ---- Phase C: PV; thread = (node nn, part, dim-pair d2); packed hfma2 ----
    {
        const int part = tl >> 6;     // 0: m 0..15, 1: m 16..31
        const int d2   = tl & 63;     // half2 index (dims 2*d2, 2*d2+1)
        const int hh2  = d2 >> 4;
        const uint* vb = (const uint*)Vh;
        __half2 a2 = as_h2(0u);
#pragma unroll
        for (int mm = 0; mm < 16; ++mm) {
            int m = part * 16 + mm;
            uint v = vb[(size_t)idx_s[nn][m] * 64 + d2];
            a2 = __hfma2(as_h2(al_u[nn][hh2][m]), as_h2(v), a2);
        }
        if (part == 1) pv1[nn][d2] = as_u(a2);
        __syncthreads();
        if (part == 0) {
            __half2 s2 = __hadd2(a2, as_h2(pv1[nn][d2]));
            rv_u[nn][d2] = as_u(s2);
        }
    }
    __syncthreads();

    // ---- Phase E: FC via MFMA; wave w = column tile w (cols 16w..16w+15) ----
    const int rl  = lane & 15;
    const int kb  = lane >> 4;
    const int col = 16 * w + rl;

    f32x4 acc = (f32x4){0.f, 0.f, 0.f, 0.f};
#pragma unroll
    for (int ks = 0; ks < 4; ++ks) {
        uint4 au = *(const uint4*)(&rv_u[rl][ks * 16 + kb * 4]);
        f16x8 af = as_f16x8(au);
        f16x8 bfr = *(const f16x8*)(WfcT + (size_t)col * DIM + ks * 32 + kb * 8);
        acc = __builtin_amdgcn_mfma_f32_16x16x32_f16(af, bfr, acc, 0, 0, 0);
    }

    // ---- Phase F: +bias +residual, GELU, LayerNorm, store ----
    // Real output rows are kb==0, j=0..3 (block's 4 nodes).
    const float bfc_c = bfc[col];
    const float gam_c = gamma[col];
    const float bet_c = beta[col];

    float g4[4], p1[4], p2[4];
#pragma unroll
    for (int j = 0; j < 4; ++j) {
        const int rsafe = j;                      // row for kb==0; harmless for kb>0
        uint qu = qsh[rsafe][col >> 1];
        __half2 qh2 = as_h2(qu);
        float qv = __half2float((col & 1) ? __high2half(qh2) : __low2half(qh2));
        float x = acc[j] + bfc_c + qv;
        float gg = 0.5f * x * (1.0f + erff(x * 0.70710678118654752f));
        g4[j] = gg;
        p1[j] = gg;
        p2[j] = gg * gg;
    }
#pragma unroll
    for (int off = 1; off < 16; off <<= 1) {
#pragma unroll
        for (int j = 0; j < 4; ++j) {
            p1[j] += __shfl_xor(p1[j], off);
            p2[j] += __shfl_xor(p2[j], off);
        }
    }
    if (lane == 0) {                              // rl==0 && kb==0
#pragma unroll
        for (int j = 0; j < 4; ++j) { red[w][j][0] = p1[j]; red[w][j][1] = p2[j]; }
    }
    __syncthreads();
    if (t < NPB) {
        float s1 = 0.f, s2 = 0.f;
#pragma unroll
        for (int ww = 0; ww < 8; ++ww) { s1 += red[ww][t][0]; s2 += red[ww][t][1]; }
        float mean = s1 * (1.0f / DIM);
        float var  = s2 * (1.0f / DIM) - mean * mean;
        tot[t][0] = mean;
        tot[t][1] = rsqrtf(var + LN_EPS);
    }
    __syncthreads();
    if (kb == 0) {
#pragma unroll
        for (int j = 0; j < 4; ++j) {
            float mean = tot[j][0], invs = tot[j][1];
            out[((size_t)b * NPB + j) * DIM + col] = (g4[j] - mean) * invs * gam_c + bet_c;
        }
    }
}

extern "C" void kernel_launch(void* const* d_in, const int* in_sizes, int n_in,
                              void* d_out, int out_size, void* d_ws, size_t ws_size,
                              hipStream_t stream) {
    (void)in_sizes; (void)n_in; (void)out_size; (void)ws_size;
    const float* h     = (const float*)d_in[0];
    const float* Wq    = (const float*)d_in[1];
    const float* Wk    = (const float*)d_in[2];
    const float* Wv    = (const float*)d_in[3];
    const float* Wfc   = (const float*)d_in[4];
    const float* bfc   = (const float*)d_in[5];
    const float* gamma = (const float*)d_in[6];
    const float* beta  = (const float*)d_in[7];
    const int* nidx    = (const int*)d_in[8];
    const int* nmask   = (const int*)d_in[9];

    f16* Kh   = (f16*)d_ws;
    f16* Vh   = Kh + (size_t)N_NODES * DIM;
    f16* Qh   = Vh + (size_t)N_NODES * DIM;
    f16* WqT  = Qh + (size_t)N_NODES * DIM;
    f16* WkT  = WqT + (size_t)DIM * DIM;
    f16* WvT  = WkT + (size_t)DIM * DIM;
    f16* WfcT = WvT + (size_t)DIM * DIM;

    prep_kernel<<<DIM, DIM, 0, stream>>>(Wq, Wk, Wv, Wfc, WqT, WkT, WvT, WfcT);
    qkv_mfma_kernel<<<(N_NODES + 63) / 64, 256, 0, stream>>>(h, WqT, WkT, WvT, Qh, Kh, Vh);
    attn_fc_kernel<<<N_NODES / NPB, 512, 0, stream>>>(Qh, Kh, Vh, nidx, nmask,
                                                      WfcT, bfc, gamma, beta, (float*)d_out);
}

// Round 8
// 119.822 us; speedup vs baseline: 1.0908x; 1.0085x over previous
//
#include <hip/hip_runtime.h>
#include <hip/hip_fp16.h>
#include <math.h>

#define N_NODES 30000
#define MAXN 32
#define DIM 128
#define NHEAD 4
#define HDIM 32
#define NPB 4            // nodes per block in fused attn+fc kernel
#define LN_EPS 1e-5f

typedef _Float16 f16;
typedef __attribute__((ext_vector_type(8))) _Float16 f16x8;
typedef __attribute__((ext_vector_type(4))) float f32x4;

static __device__ __forceinline__ __half2 as_h2(uint u) { return __builtin_bit_cast(__half2, u); }
static __device__ __forceinline__ uint as_u(__half2 h) { return __builtin_bit_cast(uint, h); }
static __device__ __forceinline__ f16x8 as_f16x8(uint4 u) { return __builtin_bit_cast(f16x8, u); }

// ---------------- prep: W[k][n] f32 -> WT[n][k] f16 for Wq,Wk,Wv,Wfc ----------------
__global__ __launch_bounds__(128) void prep_kernel(
    const float* __restrict__ Wq, const float* __restrict__ Wk,
    const float* __restrict__ Wv, const float* __restrict__ Wfc,
    f16* __restrict__ WqT, f16* __restrict__ WkT,
    f16* __restrict__ WvT, f16* __restrict__ WfcT)
{
    const int n = blockIdx.x, k = threadIdx.x;
    WqT[n * DIM + k]  = (f16)Wq[k * DIM + n];
    WkT[n * DIM + k]  = (f16)Wk[k * DIM + n];
    WvT[n * DIM + k]  = (f16)Wv[k * DIM + n];
    WfcT[n * DIM + k] = (f16)Wfc[k * DIM + n];
}

// ---------------- Kernel 1: QKV projection via MFMA (f16) ----------------
__device__ inline void gemm_pass(const f16x8 a[4], const f16* __restrict__ WT,
                                 int rl, int kb, f32x4 acc[8]) {
#pragma unroll
    for (int ks = 0; ks < 4; ++ks) {
        const f16* wp = WT + (size_t)rl * DIM + ks * 32 + kb * 8;
#pragma unroll
        for (int t = 0; t < 8; ++t) {
            f16x8 bfrag = *(const f16x8*)(wp + (size_t)t * 16 * DIM);
            acc[t] = __builtin_amdgcn_mfma_f32_16x16x32_f16(a[ks], bfrag, acc[t], 0, 0, 0);
        }
    }
}

__global__ __launch_bounds__(256) void qkv_mfma_kernel(
    const float* __restrict__ h,
    const f16* __restrict__ WqT,
    const f16* __restrict__ WkT,
    const f16* __restrict__ WvT,
    f16* __restrict__ Qout,
    f16* __restrict__ Kout,
    f16* __restrict__ Vout)
{
    const int lane = threadIdx.x & 63;
    const int wid  = threadIdx.x >> 6;
    const int r0w  = blockIdx.x * 64 + wid * 16;
    const int rl = lane & 15;
    const int kb = lane >> 4;

    const int arow = min(r0w + rl, N_NODES - 1);
    const float* hrow = h + (size_t)arow * DIM + kb * 8;
    f16x8 a[4];
#pragma unroll
    for (int ks = 0; ks < 4; ++ks) {
        float4 f0 = *(const float4*)(hrow + ks * 32);
        float4 f1 = *(const float4*)(hrow + ks * 32 + 4);
        f16x8 v;
        v[0] = (f16)f0.x; v[1] = (f16)f0.y; v[2] = (f16)f0.z; v[3] = (f16)f0.w;
        v[4] = (f16)f1.x; v[5] = (f16)f1.y; v[6] = (f16)f1.z; v[7] = (f16)f1.w;
        a[ks] = v;
    }

    f32x4 acc[8];

    // ---- Q ----
#pragma unroll
    for (int t = 0; t < 8; ++t) acc[t] = (f32x4){0.f, 0.f, 0.f, 0.f};
    gemm_pass(a, WqT, rl, kb, acc);
#pragma unroll
    for (int j = 0; j < 4; ++j) {
        const int row = r0w + kb * 4 + j;
        if (row < N_NODES) {
            f16* orow = Qout + (size_t)row * DIM;
#pragma unroll
            for (int t = 0; t < 8; ++t) orow[rl + 16 * t] = (f16)acc[t][j];
        }
    }

    // ---- K ----
#pragma unroll
    for (int t = 0; t < 8; ++t) acc[t] = (f32x4){0.f, 0.f, 0.f, 0.f};
    gemm_pass(a, WkT, rl, kb, acc);
#pragma unroll
    for (int j = 0; j < 4; ++j) {
        const int row = r0w + kb * 4 + j;
        if (row < N_NODES) {
            f16* orow = Kout + (size_t)row * DIM;
#pragma unroll
            for (int t = 0; t < 8; ++t) orow[rl + 16 * t] = (f16)acc[t][j];
        }
    }

    // ---- V ----
#pragma unroll
    for (int t = 0; t < 8; ++t) acc[t] = (f32x4){0.f, 0.f, 0.f, 0.f};
    gemm_pass(a, WvT, rl, kb, acc);
#pragma unroll
    for (int j = 0; j < 4; ++j) {
        const int row = r0w + kb * 4 + j;
        if (row < N_NODES) {
            f16* orow = Vout + (size_t)row * DIM;
#pragma unroll
            for (int t = 0; t < 8; ++t) orow[rl + 16 * t] = (f16)acc[t][j];
        }
    }
}

// ---------------- Kernel 2: fused gather-attention + FC + GELU + LN ----------------
// 512 threads, NPB=4 nodes (128 threads/node); 1-output-per-thread epilogue.
__global__ __launch_bounds__(512, 8) void attn_fc_kernel(
    const f16* __restrict__ Qh,          // [N][128] fp16 (ws)
    const f16* __restrict__ Kh,
    const f16* __restrict__ Vh,
    const int* __restrict__ nidx,
    const int* __restrict__ nmask,
    const f16* __restrict__ WfcT,        // [n][k] fp16
    const float* __restrict__ bfc,
    const float* __restrict__ gamma,
    const float* __restrict__ beta,
    float* __restrict__ out)
{
    __shared__ uint qsh[NPB][68];          // Q rows as half2 (64 uints + pad)
    __shared__ uint al_u[NPB][NHEAD][33];  // alpha as dup-half2
    __shared__ uint pv1[NPB][64];          // PV partial (part 1), half2
    __shared__ uint rv_u[16][68];          // attn out rows as half2 (rows 4..15 garbage)
    __shared__ float fcout[NPB][132];      // FC output (pre-bias), 4 real rows
    __shared__ int  idx_s[NPB][MAXN];
    __shared__ float red[8][2];            // per-wave LN partials
    __shared__ float minv[NPB][2];         // mean, invstd per node

    const int t    = threadIdx.x;
    const int b    = blockIdx.x;
    const int w    = t >> 6;        // wave 0..7
    const int lane = t & 63;
    const int nn   = t >> 7;        // node slot 0..3 (phases B/C/F)
    const int tl   = t & 127;       // thread within node

    // ---- Phase A: Q rows (fp16) + neighbor indices into LDS ----
    if (t < NPB * 64) {
        qsh[t >> 6][t & 63] = ((const uint*)Qh)[(size_t)b * (NPB * 64) + t];
    }
    if (t < NPB * MAXN) {
        idx_s[t >> 5][t & 31] = nidx[(size_t)b * (NPB * MAXN) + t];
    }
    __syncthreads();

    // ---- Phase B: scores + softmax; thread = (node nn, head hh, neighbor m) ----
    {
        const int hh = tl >> 5;
        const int m  = tl & 31;
        const int src = idx_s[nn][m];
        const uint4* krow = (const uint4*)(Kh + (size_t)src * DIM + hh * HDIM);
        const uint4* qrow = (const uint4*)(&qsh[nn][hh * 16]);

        __half2 a2 = as_h2(0u);
#pragma unroll
        for (int c = 0; c < 4; ++c) {
            uint4 kd = krow[c];
            uint4 qd = qrow[c];
            a2 = __hfma2(as_h2(qd.x), as_h2(kd.x), a2);
            a2 = __hfma2(as_h2(qd.y), as_h2(kd.y), a2);
            a2 = __hfma2(as_h2(qd.z), as_h2(kd.z), a2);
            a2 = __hfma2(as_h2(qd.w), as_h2(kd.w), a2);
        }
        float acc = __half2float(__low2half(a2)) + __half2float(__high2half(a2));
        acc *= 0.17677669529663687f;            // 1/sqrt(32)
        if (nmask[(size_t)b * (NPB * MAXN) + nn * MAXN + m] == 0) acc = -1e9f;

        float mx = acc;
#pragma unroll
        for (int off = 1; off < 32; off <<= 1)
            mx = fmaxf(mx, __shfl_xor(mx, off));
        float e = __expf(acc - mx);
        float s = e;
#pragma unroll
        for (int off = 1; off < 32; off <<= 1)
            s += __shfl_xor(s, off);
        float a = e / s;
        uint ah = (uint)__half_as_ushort(__float2half(a));
        al_u[nn][hh][m] = ah | (ah << 16);
    }
    __syncthreads();

    // ---- Phase C: PV; thread = (node nn, part, dim-pair d2); packed hfma2 ----
    {
        const int part = tl >> 6;     // 0: m 0..15, 1: m 16..31
        const int d2   = tl & 63;     // half2 index (dims 2*d2, 2*d2+1)
        const int hh2  = d2 >> 4;
        const uint* vb = (const uint*)Vh;
        __half2 a2 = as_h2(0u);
#pragma unroll
        for (int mm = 0; mm < 16; ++mm) {
            int m = part * 16 + mm;
            uint v = vb[(size_t)idx_s[nn][m] * 64 + d2];
            a2 = __hfma2(as_h2(al_u[nn][hh2][m]), as_h2(v), a2);
        }
        if (part == 1) pv1[nn][d2] = as_u(a2);
        __syncthreads();
        if (part == 0) {
            __half2 s2 = __hadd2(a2, as_h2(pv1[nn][d2]));
            rv_u[nn][d2] = as_u(s2);
        }
    }
    __syncthreads();

    // ---- Phase E: FC via MFMA; wave w = column tile w (cols 16w..16w+15) ----
    {
        const int rl  = lane & 15;
        const int kb  = lane >> 4;
        const int col = 16 * w + rl;

        f32x4 acc = (f32x4){0.f, 0.f, 0.f, 0.f};
#pragma unroll
        for (int ks = 0; ks < 4; ++ks) {
            uint4 au = *(const uint4*)(&rv_u[rl][ks * 16 + kb * 4]);
            f16x8 af = as_f16x8(au);
            f16x8 bfr = *(const f16x8*)(WfcT + (size_t)col * DIM + ks * 32 + kb * 8);
            acc = __builtin_amdgcn_mfma_f32_16x16x32_f16(af, bfr, acc, 0, 0, 0);
        }
        // real output rows are kb==0, j=0..3 (the block's 4 nodes)
        if (kb == 0) {
#pragma unroll
            for (int j = 0; j < 4; ++j) fcout[j][col] = acc[j];
        }
    }
    __syncthreads();

    // ---- Phase F: one (node, col) per thread: +bias +residual, GELU, LN ----
    {
        const int c2 = tl;                          // col 0..127, node nn
        uint qu = qsh[nn][c2 >> 1];
        __half2 qh2 = as_h2(qu);
        float qv = __half2float((c2 & 1) ? __high2half(qh2) : __low2half(qh2));
        float x = fcout[nn][c2] + bfc[c2] + qv;
        float gg = 0.5f * x * (1.0f + erff(x * 0.70710678118654752f));

        float s1 = gg, s2 = gg * gg;
#pragma unroll
        for (int off = 1; off < 64; off <<= 1) {
            s1 += __shfl_xor(s1, off);
            s2 += __shfl_xor(s2, off);
        }
        if (lane == 0) { red[w][0] = s1; red[w][1] = s2; }
        __syncthreads();
        if ((t & 63) == 0) {                        // one lane per wave; waves 2nn,2nn+1
            float ts1 = red[nn * 2][0] + red[nn * 2 + 1][0];
            float ts2 = red[nn * 2][1] + red[nn * 2 + 1][1];
            float mean = ts1 * (1.0f / DIM);
            float var  = ts2 * (1.0f / DIM) - mean * mean;
            minv[nn][0] = mean;
            minv[nn][1] = rsqrtf(var + LN_EPS);
        }
        __syncthreads();
        float mean = minv[nn][0];
        float invs = minv[nn][1];
        out[((size_t)b * NPB + nn) * DIM + c2] = (gg - mean) * invs * gamma[c2] + beta[c2];
    }
}

extern "C" void kernel_launch(void* const* d_in, const int* in_sizes, int n_in,
                              void* d_out, int out_size, void* d_ws, size_t ws_size,
                              hipStream_t stream) {
    (void)in_sizes; (void)n_in; (void)out_size; (void)ws_size;
    const float* h     = (const float*)d_in[0];
    const float* Wq    = (const float*)d_in[1];
    const float* Wk    = (const float*)d_in[2];
    const float* Wv    = (const float*)d_in[3];
    const float* Wfc   = (const float*)d_in[4];
    const float* bfc   = (const float*)d_in[5];
    const float* gamma = (const float*)d_in[6];
    const float* beta  = (const float*)d_in[7];
    const int* nidx    = (const int*)d_in[8];
    const int* nmask   = (const int*)d_in[9];

    f16* Kh   = (f16*)d_ws;
    f16* Vh   = Kh + (size_t)N_NODES * DIM;
    f16* Qh   = Vh + (size_t)N_NODES * DIM;
    f16* WqT  = Qh + (size_t)N_NODES * DIM;
    f16* WkT  = WqT + (size_t)DIM * DIM;
    f16* WvT  = WkT + (size_t)DIM * DIM;
    f16* WfcT = WvT + (size_t)DIM * DIM;

    prep_kernel<<<DIM, DIM, 0, stream>>>(Wq, Wk, Wv, Wfc, WqT, WkT, WvT, WfcT);
    qkv_mfma_kernel<<<(N_NODES + 63) / 64, 256, 0, stream>>>(h, WqT, WkT, WvT, Qh, Kh, Vh);
    attn_fc_kernel<<<N_NODES / NPB, 512, 0, stream>>>(Qh, Kh, Vh, nidx, nmask,
                                                      WfcT, bfc, gamma, beta, (float*)d_out);
}

// Round 9
// 104.384 us; speedup vs baseline: 1.2522x; 1.1479x over previous
//
#include <hip/hip_runtime.h>
#include <hip/hip_fp16.h>
#include <math.h>

#define N_NODES 30000
#define MAXN 32
#define DIM 128
#define NHEAD 4
#define HDIM 32
#define LN_EPS 1e-5f

typedef _Float16 f16;
typedef __attribute__((ext_vector_type(8))) _Float16 f16x8;
typedef __attribute__((ext_vector_type(4))) float f32x4;

static __device__ __forceinline__ __half2 as_h2(uint u) { return __builtin_bit_cast(__half2, u); }
static __device__ __forceinline__ uint as_u(__half2 h) { return __builtin_bit_cast(uint, h); }
static __device__ __forceinline__ f16x8 as_f16x8(uint4 u) { return __builtin_bit_cast(f16x8, u); }

// ---------------- prep: W[k][n] f32 -> WT[n][k] f16 for Wq,Wk,Wv,Wfc ----------------
__global__ __launch_bounds__(128) void prep_kernel(
    const float* __restrict__ Wq, const float* __restrict__ Wk,
    const float* __restrict__ Wv, const float* __restrict__ Wfc,
    f16* __restrict__ WqT, f16* __restrict__ WkT,
    f16* __restrict__ WvT, f16* __restrict__ WfcT)
{
    const int n = blockIdx.x, k = threadIdx.x;
    WqT[n * DIM + k]  = (f16)Wq[k * DIM + n];
    WkT[n * DIM + k]  = (f16)Wk[k * DIM + n];
    WvT[n * DIM + k]  = (f16)Wv[k * DIM + n];
    WfcT[n * DIM + k] = (f16)Wfc[k * DIM + n];
}

// ---------------- Kernel 1: QKV projection via MFMA, weights staged in LDS ----------------
// 256 threads = 4 waves; block handles 64 rows; W^T staged per matrix (32KB, padded).
__global__ __launch_bounds__(256) void qkv_mfma_kernel(
    const float* __restrict__ h,
    const f16* __restrict__ WqT,
    const f16* __restrict__ WkT,
    const f16* __restrict__ WvT,
    f16* __restrict__ Qout,
    f16* __restrict__ Kout,
    f16* __restrict__ Vout)
{
    __shared__ f16 wlds[DIM][136];          // 34.8 KB; stride 272B (16B-aligned, slot-uniform)

    const int lane = threadIdx.x & 63;
    const int wid  = threadIdx.x >> 6;
    const int r0w  = blockIdx.x * 64 + wid * 16;
    const int rl = lane & 15;
    const int kb = lane >> 4;

    // preload + convert A fragments: row r0w+rl, k = ks*32 + kb*8 + [0..8)
    const int arow = min(r0w + rl, N_NODES - 1);
    const float* hrow = h + (size_t)arow * DIM + kb * 8;
    f16x8 a[4];
#pragma unroll
    for (int ks = 0; ks < 4; ++ks) {
        float4 f0 = *(const float4*)(hrow + ks * 32);
        float4 f1 = *(const float4*)(hrow + ks * 32 + 4);
        f16x8 v;
        v[0] = (f16)f0.x; v[1] = (f16)f0.y; v[2] = (f16)f0.z; v[3] = (f16)f0.w;
        v[4] = (f16)f1.x; v[5] = (f16)f1.y; v[6] = (f16)f1.z; v[7] = (f16)f1.w;
        a[ks] = v;
    }

    f32x4 acc[8];

#define STAGE_W(WT)                                                         \
    {                                                                       \
        const uint4* s4 = (const uint4*)(WT);                               \
        _Pragma("unroll")                                                   \
        for (int i = 0; i < 8; ++i) {                                       \
            int L = i * 256 + (int)threadIdx.x;   /* 2048 uint4 = 32KB */   \
            *(uint4*)(&wlds[L >> 4][(L & 15) * 8]) = s4[L];                 \
        }                                                                   \
    }

#define GEMM_LDS()                                                          \
    _Pragma("unroll")                                                       \
    for (int tc = 0; tc < 8; ++tc) acc[tc] = (f32x4){0.f, 0.f, 0.f, 0.f};   \
    _Pragma("unroll")                                                       \
    for (int ks = 0; ks < 4; ++ks) {                                        \
        _Pragma("unroll")                                                   \
        for (int tc = 0; tc < 8; ++tc) {                                    \
            f16x8 bfrag = *(const f16x8*)(&wlds[rl + 16 * tc][ks * 32 + kb * 8]); \
            acc[tc] = __builtin_amdgcn_mfma_f32_16x16x32_f16(a[ks], bfrag, acc[tc], 0, 0, 0); \
        }                                                                   \
    }

#define STORE_OUT(OUT)                                                      \
    _Pragma("unroll")                                                       \
    for (int j = 0; j < 4; ++j) {                                           \
        const int row = r0w + kb * 4 + j;                                   \
        if (row < N_NODES) {                                                \
            f16* orow = (OUT) + (size_t)row * DIM;                          \
            _Pragma("unroll")                                               \
            for (int tc = 0; tc < 8; ++tc) orow[rl + 16 * tc] = (f16)acc[tc][j]; \
        }                                                                   \
    }

    // ---- Q ----
    STAGE_W(WqT);
    __syncthreads();
    GEMM_LDS();
    STORE_OUT(Qout);
    __syncthreads();
    // ---- K ----
    STAGE_W(WkT);
    __syncthreads();
    GEMM_LDS();
    STORE_OUT(Kout);
    __syncthreads();
    // ---- V ----
    STAGE_W(WvT);
    __syncthreads();
    GEMM_LDS();
    STORE_OUT(Vout);
}

// ---------------- Kernel 2: fused gather-attention + FC + GELU + LN ----------------
// 512 threads = 8 waves = 8 nodes; gather phases wave-local (0 barriers), 2 barriers total.
__global__ __launch_bounds__(512, 8) void attn_fc_kernel(
    const f16* __restrict__ Qh,          // [N][128] fp16 (ws)
    const f16* __restrict__ Kh,
    const f16* __restrict__ Vh,
    const int* __restrict__ nidx,
    const int* __restrict__ nmask,
    const f16* __restrict__ WfcT,        // [n][k] fp16
    const float* __restrict__ bfc,
    const float* __restrict__ gamma,
    const float* __restrict__ beta,
    float* __restrict__ out)
{
    __shared__ uint  qsh[8][68];          // Q rows as half2
    __shared__ uint  al_u[8][NHEAD][33];  // alpha as dup-half2
    __shared__ uint  rv_u[8][68];         // attn-out rows as half2
    __shared__ float fcout[8][132];       // FC output (pre-bias)
    __shared__ int   idx_s[8][MAXN];

    const int t    = threadIdx.x;
    const int b    = blockIdx.x;
    const int w    = t >> 6;        // wave = node slot 0..7
    const int lane = t & 63;
    const int node = b * 8 + w;

    // ---- Phase A (wave-local): Q row + neighbor idx/mask ----
    qsh[w][lane] = ((const uint*)Qh)[(size_t)node * 64 + lane];
    const int m   = lane & 31;
    const int hh2 = lane >> 5;
    const int src = nidx[(size_t)node * MAXN + m];
    const int msk = nmask[(size_t)node * MAXN + m];
    if (lane < 32) idx_s[w][lane] = src;

    // ---- Phase B (wave-local): scores for heads {hh2, hh2+2} + softmax ----
    float sc[2];
#pragma unroll
    for (int hp = 0; hp < 2; ++hp) {
        const int hh = hh2 + 2 * hp;
        const uint4* krow = (const uint4*)(Kh + (size_t)src * DIM + hh * HDIM);
        const uint4* qrow = (const uint4*)(&qsh[w][hh * 16]);
        __half2 a2 = as_h2(0u);
#pragma unroll
        for (int c = 0; c < 4; ++c) {
            uint4 kd = krow[c];
            uint4 qd = qrow[c];
            a2 = __hfma2(as_h2(qd.x), as_h2(kd.x), a2);
            a2 = __hfma2(as_h2(qd.y), as_h2(kd.y), a2);
            a2 = __hfma2(as_h2(qd.z), as_h2(kd.z), a2);
            a2 = __hfma2(as_h2(qd.w), as_h2(kd.w), a2);
        }
        float acc = __half2float(__low2half(a2)) + __half2float(__high2half(a2));
        acc *= 0.17677669529663687f;            // 1/sqrt(32)
        sc[hp] = (msk == 0) ? -1e9f : acc;
    }
#pragma unroll
    for (int hp = 0; hp < 2; ++hp) {
        float mx = sc[hp];
#pragma unroll
        for (int off = 1; off < 32; off <<= 1)
            mx = fmaxf(mx, __shfl_xor(mx, off));
        float e = __expf(sc[hp] - mx);
        float s = e;
#pragma unroll
        for (int off = 1; off < 32; off <<= 1)
            s += __shfl_xor(s, off);
        float av = e / s;
        uint ah = (uint)__half_as_ushort(__float2half(av));
        al_u[w][hh2 + 2 * hp][m] = ah | (ah << 16);
    }

    // ---- Phase C (wave-local): PV; lane = dim-pair d2, all 32 neighbors ----
    {
        const int d2 = lane;
        const int hh = d2 >> 4;
        const uint* vb = (const uint*)Vh;
        __half2 a2 = as_h2(0u);
#pragma unroll
        for (int mm = 0; mm < MAXN; ++mm) {
            int sm = idx_s[w][mm];
            uint v = vb[(size_t)sm * 64 + d2];
            a2 = __hfma2(as_h2(al_u[w][hh][mm]), as_h2(v), a2);
        }
        rv_u[w][d2] = as_u(a2);
    }
    __syncthreads();

    // ---- Phase E: FC via MFMA; wave w = column tile w (8 real rows, 8 zero) ----
    {
        const int rl  = lane & 15;
        const int kb  = lane >> 4;
        const int col = 16 * w + rl;

        f32x4 acc = (f32x4){0.f, 0.f, 0.f, 0.f};
#pragma unroll
        for (int ks = 0; ks < 4; ++ks) {
            uint4 au = *(const uint4*)(&rv_u[rl & 7][ks * 16 + kb * 4]);
            if (rl >= 8) au = (uint4){0u, 0u, 0u, 0u};
            f16x8 af = as_f16x8(au);
            f16x8 bfr = *(const f16x8*)(WfcT + (size_t)col * DIM + ks * 32 + kb * 8);
            acc = __builtin_amdgcn_mfma_f32_16x16x32_f16(af, bfr, acc, 0, 0, 0);
        }
        if (kb < 2) {                               // rows kb*4+j = 0..7 are real
#pragma unroll
            for (int j = 0; j < 4; ++j) fcout[kb * 4 + j][col] = acc[j];
        }
    }
    __syncthreads();

    // ---- Phase F (wave-local): wave w = node w; 2 cols/lane; in-wave LN ----
    {
        float g2[2];
        float s1 = 0.f, s2 = 0.f;
#pragma unroll
        for (int p = 0; p < 2; ++p) {
            const int c = lane + 64 * p;
            __half2 qh2 = as_h2(qsh[w][c >> 1]);
            float qv = __half2float((c & 1) ? __high2half(qh2) : __low2half(qh2));
            float x = fcout[w][c] + bfc[c] + qv;
            float gg = 0.5f * x * (1.0f + erff(x * 0.70710678118654752f));
            g2[p] = gg;
            s1 += gg;
            s2 += gg * gg;
        }
#pragma unroll
        for (int off = 1; off < 64; off <<= 1) {
            s1 += __shfl_xor(s1, off);
            s2 += __shfl_xor(s2, off);
        }
        float mean = s1 * (1.0f / DIM);
        float var  = s2 * (1.0f / DIM) - mean * mean;
        float invs = rsqrtf(var + LN_EPS);
#pragma unroll
        for (int p = 0; p < 2; ++p) {
            const int c = lane + 64 * p;
            out[(size_t)node * DIM + c] = (g2[p] - mean) * invs * gamma[c] + beta[c];
        }
    }
}

extern "C" void kernel_launch(void* const* d_in, const int* in_sizes, int n_in,
                              void* d_out, int out_size, void* d_ws, size_t ws_size,
                              hipStream_t stream) {
    (void)in_sizes; (void)n_in; (void)out_size; (void)ws_size;
    const float* h     = (const float*)d_in[0];
    const float* Wq    = (const float*)d_in[1];
    const float* Wk    = (const float*)d_in[2];
    const float* Wv    = (const float*)d_in[3];
    const float* Wfc   = (const float*)d_in[4];
    const float* bfc   = (const float*)d_in[5];
    const float* gamma = (const float*)d_in[6];
    const float* beta  = (const float*)d_in[7];
    const int* nidx    = (const int*)d_in[8];
    const int* nmask   = (const int*)d_in[9];

    f16* Kh   = (f16*)d_ws;
    f16* Vh   = Kh + (size_t)N_NODES * DIM;
    f16* Qh   = Vh + (size_t)N_NODES * DIM;
    f16* WqT  = Qh + (size_t)N_NODES * DIM;
    f16* WkT  = WqT + (size_t)DIM * DIM;
    f16* WvT  = WkT + (size_t)DIM * DIM;
    f16* WfcT = WvT + (size_t)DIM * DIM;

    prep_kernel<<<DIM, DIM, 0, stream>>>(Wq, Wk, Wv, Wfc, WqT, WkT, WvT, WfcT);
    qkv_mfma_kernel<<<(N_NODES + 63) / 64, 256, 0, stream>>>(h, WqT, WkT, WvT, Qh, Kh, Vh);
    attn_fc_kernel<<<N_NODES / 8, 512, 0, stream>>>(Qh, Kh, Vh, nidx, nmask,
                                                    WfcT, bfc, gamma, beta, (float*)d_out);
}

// Round 10
// 102.400 us; speedup vs baseline: 1.2764x; 1.0194x over previous
//
#include <hip/hip_runtime.h>
#include <hip/hip_fp16.h>
#include <math.h>

#define N_NODES 30000
#define MAXN 32
#define DIM 128
#define NHEAD 4
#define HDIM 32
#define LN_EPS 1e-5f

typedef _Float16 f16;
typedef __attribute__((ext_vector_type(8))) _Float16 f16x8;
typedef __attribute__((ext_vector_type(4))) float f32x4;

static __device__ __forceinline__ __half2 as_h2(uint u) { return __builtin_bit_cast(__half2, u); }
static __device__ __forceinline__ uint as_u(__half2 h) { return __builtin_bit_cast(uint, h); }
static __device__ __forceinline__ f16x8 as_f16x8(uint4 u) { return __builtin_bit_cast(f16x8, u); }

// ---------------- prep: W[k][n] f32 -> WT[n][k] f16 for Wq,Wk,Wv,Wfc ----------------
__global__ __launch_bounds__(128) void prep_kernel(
    const float* __restrict__ Wq, const float* __restrict__ Wk,
    const float* __restrict__ Wv, const float* __restrict__ Wfc,
    f16* __restrict__ WqT, f16* __restrict__ WkT,
    f16* __restrict__ WvT, f16* __restrict__ WfcT)
{
    const int n = blockIdx.x, k = threadIdx.x;
    WqT[n * DIM + k]  = (f16)Wq[k * DIM + n];
    WkT[n * DIM + k]  = (f16)Wk[k * DIM + n];
    WvT[n * DIM + k]  = (f16)Wv[k * DIM + n];
    WfcT[n * DIM + k] = (f16)Wfc[k * DIM + n];
}

// ---------------- Kernel 1: QKV projection via MFMA, weights staged in LDS ----------------
__global__ __launch_bounds__(256) void qkv_mfma_kernel(
    const float* __restrict__ h,
    const f16* __restrict__ WqT,
    const f16* __restrict__ WkT,
    const f16* __restrict__ WvT,
    f16* __restrict__ Qout,
    f16* __restrict__ Kout,
    f16* __restrict__ Vout)
{
    __shared__ f16 wlds[DIM][136];

    const int lane = threadIdx.x & 63;
    const int wid  = threadIdx.x >> 6;
    const int r0w  = blockIdx.x * 64 + wid * 16;
    const int rl = lane & 15;
    const int kb = lane >> 4;

    const int arow = min(r0w + rl, N_NODES - 1);
    const float* hrow = h + (size_t)arow * DIM + kb * 8;
    f16x8 a[4];
#pragma unroll
    for (int ks = 0; ks < 4; ++ks) {
        float4 f0 = *(const float4*)(hrow + ks * 32);
        float4 f1 = *(const float4*)(hrow + ks * 32 + 4);
        f16x8 v;
        v[0] = (f16)f0.x; v[1] = (f16)f0.y; v[2] = (f16)f0.z; v[3] = (f16)f0.w;
        v[4] = (f16)f1.x; v[5] = (f16)f1.y; v[6] = (f16)f1.z; v[7] = (f16)f1.w;
        a[ks] = v;
    }

    f32x4 acc[8];

#define STAGE_W(WT)                                                         \
    {                                                                       \
        const uint4* s4 = (const uint4*)(WT);                               \
        _Pragma("unroll")                                                   \
        for (int i = 0; i < 8; ++i) {                                       \
            int L = i * 256 + (int)threadIdx.x;                             \
            *(uint4*)(&wlds[L >> 4][(L & 15) * 8]) = s4[L];                 \
        }                                                                   \
    }

#define GEMM_LDS()                                                          \
    _Pragma("unroll")                                                       \
    for (int tc = 0; tc < 8; ++tc) acc[tc] = (f32x4){0.f, 0.f, 0.f, 0.f};   \
    _Pragma("unroll")                                                       \
    for (int ks = 0; ks < 4; ++ks) {                                        \
        _Pragma("unroll")                                                   \
        for (int tc = 0; tc < 8; ++tc) {                                    \
            f16x8 bfrag = *(const f16x8*)(&wlds[rl + 16 * tc][ks * 32 + kb * 8]); \
            acc[tc] = __builtin_amdgcn_mfma_f32_16x16x32_f16(a[ks], bfrag, acc[tc], 0, 0, 0); \
        }                                                                   \
    }

#define STORE_OUT(OUT)                                                      \
    _Pragma("unroll")                                                       \
    for (int j = 0; j < 4; ++j) {                                           \
        const int row = r0w + kb * 4 + j;                                   \
        if (row < N_NODES) {                                                \
            f16* orow = (OUT) + (size_t)row * DIM;                          \
            _Pragma("unroll")                                               \
            for (int tc = 0; tc < 8; ++tc) orow[rl + 16 * tc] = (f16)acc[tc][j]; \
        }                                                                   \
    }

    STAGE_W(WqT);
    __syncthreads();
    GEMM_LDS();
    STORE_OUT(Qout);
    __syncthreads();
    STAGE_W(WkT);
    __syncthreads();
    GEMM_LDS();
    STORE_OUT(Kout);
    __syncthreads();
    STAGE_W(WvT);
    __syncthreads();
    GEMM_LDS();
    STORE_OUT(Vout);
}

// ---------------- Kernel 2: fused gather-attention + FC + GELU + LN ----------------
// 512 threads = 8 waves = 16 nodes; 2 nodes per wave, interleaved load streams (2x MLP).
__global__ __launch_bounds__(512, 8) void attn_fc_kernel(
    const f16* __restrict__ Qh,          // [N][128] fp16 (ws)
    const f16* __restrict__ Kh,
    const f16* __restrict__ Vh,
    const int* __restrict__ nidx,
    const int* __restrict__ nmask,
    const f16* __restrict__ WfcT,        // [n][k] fp16
    const float* __restrict__ bfc,
    const float* __restrict__ gamma,
    const float* __restrict__ beta,
    float* __restrict__ out)
{
    __shared__ uint  qsh[16][68];          // Q rows as half2
    __shared__ uint  al_u[16][NHEAD][33];  // alpha as dup-half2
    __shared__ uint  rv_u[16][68];         // attn-out rows as half2
    __shared__ float fcout[16][132];       // FC output (pre-bias)
    __shared__ int   idx_s[16][MAXN];

    const int t    = threadIdx.x;
    const int b    = blockIdx.x;
    const int w    = t >> 6;        // wave 0..7; owns nodes 2w, 2w+1
    const int lane = t & 63;
    const int nA   = b * 16 + 2 * w;
    const int nB   = nA + 1;

    // ---- Phase A (wave-local): Q rows + neighbor idx/mask for both nodes ----
    qsh[2 * w][lane]     = ((const uint*)Qh)[(size_t)nA * 64 + lane];
    qsh[2 * w + 1][lane] = ((const uint*)Qh)[(size_t)nB * 64 + lane];
    const int m   = lane & 31;
    const int hh2 = lane >> 5;
    const int srcA = nidx[(size_t)nA * MAXN + m];
    const int srcB = nidx[(size_t)nB * MAXN + m];
    const int mskA = nmask[(size_t)nA * MAXN + m];
    const int mskB = nmask[(size_t)nB * MAXN + m];
    if (lane < 32) {
        idx_s[2 * w][m]     = srcA;
        idx_s[2 * w + 1][m] = srcB;
    }

    // ---- Phase B (wave-local): scores for heads {hh2, hh2+2}, both nodes ----
    float scA[2], scB[2];
#pragma unroll
    for (int hp = 0; hp < 2; ++hp) {
        const int hh = hh2 + 2 * hp;
        const uint4* kAr = (const uint4*)(Kh + (size_t)srcA * DIM + hh * HDIM);
        const uint4* kBr = (const uint4*)(Kh + (size_t)srcB * DIM + hh * HDIM);
        const uint4* qAr = (const uint4*)(&qsh[2 * w][hh * 16]);
        const uint4* qBr = (const uint4*)(&qsh[2 * w + 1][hh * 16]);
        __half2 aA = as_h2(0u), aB = as_h2(0u);
#pragma unroll
        for (int c = 0; c < 4; ++c) {
            uint4 kdA = kAr[c];
            uint4 kdB = kBr[c];
            uint4 qdA = qAr[c];
            uint4 qdB = qBr[c];
            aA = __hfma2(as_h2(qdA.x), as_h2(kdA.x), aA);
            aB = __hfma2(as_h2(qdB.x), as_h2(kdB.x), aB);
            aA = __hfma2(as_h2(qdA.y), as_h2(kdA.y), aA);
            aB = __hfma2(as_h2(qdB.y), as_h2(kdB.y), aB);
            aA = __hfma2(as_h2(qdA.z), as_h2(kdA.z), aA);
            aB = __hfma2(as_h2(qdB.z), as_h2(kdB.z), aB);
            aA = __hfma2(as_h2(qdA.w), as_h2(kdA.w), aA);
            aB = __hfma2(as_h2(qdB.w), as_h2(kdB.w), aB);
        }
        float accA = __half2float(__low2half(aA)) + __half2float(__high2half(aA));
        float accB = __half2float(__low2half(aB)) + __half2float(__high2half(aB));
        accA *= 0.17677669529663687f;
        accB *= 0.17677669529663687f;
        scA[hp] = (mskA == 0) ? -1e9f : accA;
        scB[hp] = (mskB == 0) ? -1e9f : accB;
    }
#pragma unroll
    for (int hp = 0; hp < 2; ++hp) {
        float mxA = scA[hp], mxB = scB[hp];
#pragma unroll
        for (int off = 1; off < 32; off <<= 1) {
            mxA = fmaxf(mxA, __shfl_xor(mxA, off));
            mxB = fmaxf(mxB, __shfl_xor(mxB, off));
        }
        float eA = __expf(scA[hp] - mxA);
        float eB = __expf(scB[hp] - mxB);
        float sA = eA, sB = eB;
#pragma unroll
        for (int off = 1; off < 32; off <<= 1) {
            sA += __shfl_xor(sA, off);
            sB += __shfl_xor(sB, off);
        }
        uint ahA = (uint)__half_as_ushort(__float2half(eA / sA));
        uint ahB = (uint)__half_as_ushort(__float2half(eB / sB));
        al_u[2 * w][hh2 + 2 * hp][m]     = ahA | (ahA << 16);
        al_u[2 * w + 1][hh2 + 2 * hp][m] = ahB | (ahB << 16);
    }

    // ---- Phase C (wave-local): PV; lane = dim-pair d2; both nodes interleaved ----
    {
        const int d2 = lane;
        const int hh = d2 >> 4;
        const uint* vb = (const uint*)Vh;
        __half2 aA = as_h2(0u), aB = as_h2(0u);
#pragma unroll
        for (int mm = 0; mm < MAXN; ++mm) {
            int sA = idx_s[2 * w][mm];
            int sB = idx_s[2 * w + 1][mm];
            uint vA = vb[(size_t)sA * 64 + d2];
            uint vB = vb[(size_t)sB * 64 + d2];
            aA = __hfma2(as_h2(al_u[2 * w][hh][mm]), as_h2(vA), aA);
            aB = __hfma2(as_h2(al_u[2 * w + 1][hh][mm]), as_h2(vB), aB);
        }
        rv_u[2 * w][d2]     = as_u(aA);
        rv_u[2 * w + 1][d2] = as_u(aB);
    }
    __syncthreads();

    // ---- Phase E: FC via MFMA; wave w = column tile w; 16 real rows ----
    {
        const int rl  = lane & 15;
        const int kb  = lane >> 4;
        const int col = 16 * w + rl;

        f32x4 acc = (f32x4){0.f, 0.f, 0.f, 0.f};
#pragma unroll
        for (int ks = 0; ks < 4; ++ks) {
            uint4 au = *(const uint4*)(&rv_u[rl][ks * 16 + kb * 4]);
            f16x8 af = as_f16x8(au);
            f16x8 bfr = *(const f16x8*)(WfcT + (size_t)col * DIM + ks * 32 + kb * 8);
            acc = __builtin_amdgcn_mfma_f32_16x16x32_f16(af, bfr, acc, 0, 0, 0);
        }
#pragma unroll
        for (int j = 0; j < 4; ++j) fcout[kb * 4 + j][col] = acc[j];
    }
    __syncthreads();

    // ---- Phase F: 2 nodes per wave (32-lane groups); 4 cols/lane; in-group LN ----
    {
        const int p  = lane >> 5;            // node parity
        const int nf = 2 * w + p;
        const int m5 = lane & 31;

        float g4[4];
        float s1 = 0.f, s2 = 0.f;
#pragma unroll
        for (int cc = 0; cc < 4; ++cc) {
            const int c = m5 + 32 * cc;
            __half2 qh2 = as_h2(qsh[nf][c >> 1]);
            float qv = __half2float((c & 1) ? __high2half(qh2) : __low2half(qh2));
            float x = fcout[nf][c] + bfc[c] + qv;
            float gg = 0.5f * x * (1.0f + erff(x * 0.70710678118654752f));
            g4[cc] = gg;
            s1 += gg;
            s2 += gg * gg;
        }
#pragma unroll
        for (int off = 1; off < 32; off <<= 1) {
            s1 += __shfl_xor(s1, off);
            s2 += __shfl_xor(s2, off);
        }
        float mean = s1 * (1.0f / DIM);
        float var  = s2 * (1.0f / DIM) - mean * mean;
        float invs = rsqrtf(var + LN_EPS);
        const int node_f = b * 16 + nf;
#pragma unroll
        for (int cc = 0; cc < 4; ++cc) {
            const int c = m5 + 32 * cc;
            out[(size_t)node_f * DIM + c] = (g4[cc] - mean) * invs * gamma[c] + beta[c];
        }
    }
}

extern "C" void kernel_launch(void* const* d_in, const int* in_sizes, int n_in,
                              void* d_out, int out_size, void* d_ws, size_t ws_size,
                              hipStream_t stream) {
    (void)in_sizes; (void)n_in; (void)out_size; (void)ws_size;
    const float* h     = (const float*)d_in[0];
    const float* Wq    = (const float*)d_in[1];
    const float* Wk    = (const float*)d_in[2];
    const float* Wv    = (const float*)d_in[3];
    const float* Wfc   = (const float*)d_in[4];
    const float* bfc   = (const float*)d_in[5];
    const float* gamma = (const float*)d_in[6];
    const float* beta  = (const float*)d_in[7];
    const int* nidx    = (const int*)d_in[8];
    const int* nmask   = (const int*)d_in[9];

    f16* Kh   = (f16*)d_ws;
    f16* Vh   = Kh + (size_t)N_NODES * DIM;
    f16* Qh   = Vh + (size_t)N_NODES * DIM;
    f16* WqT  = Qh + (size_t)N_NODES * DIM;
    f16* WkT  = WqT + (size_t)DIM * DIM;
    f16* WvT  = WkT + (size_t)DIM * DIM;
    f16* WfcT = WvT + (size_t)DIM * DIM;

    prep_kernel<<<DIM, DIM, 0, stream>>>(Wq, Wk, Wv, Wfc, WqT, WkT, WvT, WfcT);
    qkv_mfma_kernel<<<(N_NODES + 63) / 64, 256, 0, stream>>>(h, WqT, WkT, WvT, Qh, Kh, Vh);
    attn_fc_kernel<<<N_NODES / 16, 512, 0, stream>>>(Qh, Kh, Vh, nidx, nmask,
                                                     WfcT, bfc, gamma, beta, (float*)d_out);
}